// Round 1
// baseline (54.005 us; speedup 1.0000x reference)
//
#include <hip/hip_runtime.h>

// out[n,k] = sum_{i,j} x[n,i] * W[k,i,j] * x[n,j]
// N = 262144 rows, D = 32.
// Recast as GEMM: z[n, p=i*32+j] = x[n,i]*x[n,j];  out = z (N x 1024) @ Wf (1024 x 32),
// Wf[p][k] = W[k*1024 + p]. Computed with v_mfma_f32_32x32x16_bf16, fp32 accumulate.

typedef __bf16 bf16x8 __attribute__((ext_vector_type(8)));
typedef float  f32x16 __attribute__((ext_vector_type(16)));

static __device__ __forceinline__ unsigned short f32_to_bf16_bits(float f) {
    __bf16 h = (__bf16)f;               // RNE conversion
    return __builtin_bit_cast(unsigned short, h);
}

// 512 threads = 8 waves; each wave does 2 tiles of 32 rows -> 512 rows/block.
// launch_bounds(512, 4): 4 waves/SIMD -> <=128 VGPR -> 2 blocks/CU (LDS: 2 x 64 KiB).
__global__ __launch_bounds__(512, 4)
void quadform_kernel(const float* __restrict__ x,
                     const float* __restrict__ W,
                     float* __restrict__ out) {
    // B-fragment table: btab[(s*64 + lane)*8 + b] holds bf16 of
    // Wf[16*s + (lane>>5)*8 + b][lane&31]  (s = 0..63 K-steps of 16)
    __shared__ __align__(16) unsigned short btab[64 * 64 * 8];   // 64 KiB

    const int tid = threadIdx.x;

    // ---- build LDS B-table from global W (fp32) ----
    #pragma unroll
    for (int f = 0; f < 8; ++f) {
        int idx = tid + f * 512;                 // 0..4095 fragments (s,l)
        int s = idx >> 6;
        int l = idx & 63;
        const float* src = W + (l & 31) * 1024 + s * 16 + ((l >> 5) << 3);
        float4 w0 = *(const float4*)(src);
        float4 w1 = *(const float4*)(src + 4);
        union { unsigned short us[8]; uint4 u4; } pk;
        pk.us[0] = f32_to_bf16_bits(w0.x);
        pk.us[1] = f32_to_bf16_bits(w0.y);
        pk.us[2] = f32_to_bf16_bits(w0.z);
        pk.us[3] = f32_to_bf16_bits(w0.w);
        pk.us[4] = f32_to_bf16_bits(w1.x);
        pk.us[5] = f32_to_bf16_bits(w1.y);
        pk.us[6] = f32_to_bf16_bits(w1.z);
        pk.us[7] = f32_to_bf16_bits(w1.w);
        *(uint4*)(&btab[idx * 8]) = pk.u4;
    }
    __syncthreads();

    const int lane = tid & 63;
    const int wave = tid >> 6;
    const int hi   = lane >> 5;     // which half-wave (selects k-chunk of fragments)
    const int rl   = lane & 31;     // row within tile / output col
    const int rowbase = blockIdx.x * 512 + wave * 64;

    unsigned int xpk[2][16];   // lane's x row, packed bf16 pairs (static-indexed)
    float        xj [2][16];   // lane's 16 j-values (fp32) for A-fragment products
    f32x16       acc[2];

    #pragma unroll
    for (int r = 0; r < 2; ++r) {
        int n = rowbase + r * 32 + rl;
        const float4* xr = (const float4*)(x + (size_t)n * 32);
        float xv[32];
        #pragma unroll
        for (int c = 0; c < 8; ++c) {
            float4 v = xr[c];
            xv[4 * c + 0] = v.x;
            xv[4 * c + 1] = v.y;
            xv[4 * c + 2] = v.z;
            xv[4 * c + 3] = v.w;
        }
        // j-values this lane supplies: j = (s&1)*16 + hi*8 + b
        #pragma unroll
        for (int b = 0; b < 8; ++b) {
            xj[r][b]     = hi ? xv[8 + b]  : xv[b];
            xj[r][8 + b] = hi ? xv[24 + b] : xv[16 + b];
        }
        // packed bf16 copy of the full row (source of the per-step scalar x_i)
        #pragma unroll
        for (int c = 0; c < 16; ++c) {
            unsigned int lo = f32_to_bf16_bits(xv[2 * c + 0]);
            unsigned int hh = f32_to_bf16_bits(xv[2 * c + 1]);
            xpk[r][c] = lo | (hh << 16);
        }
        #pragma unroll
        for (int e = 0; e < 16; ++e) acc[r][e] = 0.0f;
    }

    // ---- main K loop: 64 steps of K=16 (p = 16s .. 16s+15), fully unrolled ----
    #pragma unroll
    for (int s = 0; s < 64; ++s) {
        bf16x8 bfrag = *(const bf16x8*)(&btab[(s * 64 + lane) * 8]);
        const int i    = s >> 1;         // p = i*32 + j ; i fixed within step
        const int hsel = (s & 1) * 8;    // which 8 of the lane's j-values
        #pragma unroll
        for (int r = 0; r < 2; ++r) {
            unsigned int w  = xpk[r][i >> 1];
            unsigned int xb = (i & 1) ? (w & 0xffff0000u) : (w << 16);
            float xi = __builtin_bit_cast(float, xb);   // x[n,i] (bf16 precision)
            bf16x8 a;
            #pragma unroll
            for (int b = 0; b < 8; ++b)
                a[b] = (__bf16)(xi * xj[r][hsel + b]);  // z[n, p] in bf16
            acc[r] = __builtin_amdgcn_mfma_f32_32x32x16_bf16(a, bfrag, acc[r], 0, 0, 0);
        }
    }

    // ---- store: D col = lane&31 (k), row = (e&3) + 8*(e>>2) + 4*hi (n offset) ----
    #pragma unroll
    for (int r = 0; r < 2; ++r) {
        int n0 = rowbase + r * 32;
        #pragma unroll
        for (int e = 0; e < 16; ++e) {
            int row = (e & 3) + 8 * (e >> 2) + 4 * hi;
            out[(size_t)(n0 + row) * 32 + rl] = acc[r][e];
        }
    }
}

extern "C" void kernel_launch(void* const* d_in, const int* in_sizes, int n_in,
                              void* d_out, int out_size, void* d_ws, size_t ws_size,
                              hipStream_t stream) {
    const float* x = (const float*)d_in[0];
    const float* W = (const float*)d_in[1];
    float* out = (float*)d_out;
    int nrows = in_sizes[0] / 32;          // 262144
    int grid  = nrows / 512;               // 512 blocks (2 per CU)
    quadform_kernel<<<grid, 512, 0, stream>>>(x, W, out);
}

// Round 2
// 51.741 us; speedup vs baseline: 1.0438x; 1.0438x over previous
//
#include <hip/hip_runtime.h>

// out[n,k] = sum_{i,j} x[n,i] * W[k,i,j] * x[n,j]   (N=262144 rows, D=32)
// GEMM form: z[n, p=i*32+j] = x[n,i]*x[n,j];  out = z (N x 1024) @ Wf (1024 x 32),
// Wf[p][k] = W[k*1024 + p]. v_mfma_f32_32x32x16_bf16, fp32 accumulate.
//
// R2 change vs R1: __launch_bounds__(512,4) capped the wave at 128 regs while
// live state is ~115 -> scratch spill (rocprof: VGPR=64, WRITE_SIZE 128MB vs
// 33MB ideal, MfmaUtil 10%). Relax to (512,2); LDS (64KiB/block) remains the
// occupancy limiter at 2 blocks/CU = 4 waves/SIMD, which is what we had anyway.

typedef __bf16 bf16x8 __attribute__((ext_vector_type(8)));
typedef float  f32x16 __attribute__((ext_vector_type(16)));

static __device__ __forceinline__ unsigned short f32_to_bf16_bits(float f) {
    __bf16 h = (__bf16)f;               // RNE conversion
    return __builtin_bit_cast(unsigned short, h);
}
static __device__ __forceinline__ unsigned int pack2_bf16(float lo, float hi) {
    return (unsigned int)f32_to_bf16_bits(lo) |
           ((unsigned int)f32_to_bf16_bits(hi) << 16);
}

__global__ __launch_bounds__(512, 2)
void quadform_kernel(const float* __restrict__ x,
                     const float* __restrict__ W,
                     float* __restrict__ out) {
    // btab[(s*64 + lane)*8 + b] = bf16 Wf[16*s + (lane>>5)*8 + b][lane&31]
    __shared__ __align__(16) unsigned short btab[64 * 64 * 8];   // 64 KiB

    const int tid  = threadIdx.x;
    const int lane = tid & 63;
    const int wave = tid >> 6;
    const int hi   = lane >> 5;
    const int rl   = lane & 31;
    const long rowbase = (long)blockIdx.x * 512 + wave * 64;

    // ---- issue both row-tiles' x loads up front (latency hides under table build)
    float4 xv4[2][8];
    #pragma unroll
    for (int r = 0; r < 2; ++r) {
        const float4* xr = (const float4*)(x + (rowbase + r * 32 + rl) * 32);
        #pragma unroll
        for (int c = 0; c < 8; ++c) xv4[r][c] = xr[c];
    }

    // ---- build LDS B-table from global W (fp32 -> bf16 fragments) ----
    #pragma unroll
    for (int f = 0; f < 8; ++f) {
        int idx = tid + f * 512;                 // 0..4095 fragments (s,l)
        int s = idx >> 6;
        int l = idx & 63;
        const float* src = W + (l & 31) * 1024 + s * 16 + ((l >> 5) << 3);
        float4 w0 = *(const float4*)(src);
        float4 w1 = *(const float4*)(src + 4);
        union { unsigned int ui[4]; uint4 u4; } pk;
        pk.ui[0] = pack2_bf16(w0.x, w0.y);
        pk.ui[1] = pack2_bf16(w0.z, w0.w);
        pk.ui[2] = pack2_bf16(w1.x, w1.y);
        pk.ui[3] = pack2_bf16(w1.z, w1.w);
        *(uint4*)(&btab[idx * 8]) = pk.u4;
    }

    // ---- per-tile x processing: packed bf16 row (16 regs) + 16 f32 j-values
    unsigned int xpk[2][16];   // static-indexed after unroll
    float        xj [2][16];
    #pragma unroll
    for (int r = 0; r < 2; ++r) {
        float xv[32];
        #pragma unroll
        for (int c = 0; c < 8; ++c) {
            xv[4 * c + 0] = xv4[r][c].x;
            xv[4 * c + 1] = xv4[r][c].y;
            xv[4 * c + 2] = xv4[r][c].z;
            xv[4 * c + 3] = xv4[r][c].w;
        }
        // j-values this lane supplies to A-fragments: j = (s&1)*16 + hi*8 + b
        #pragma unroll
        for (int b = 0; b < 8; ++b) {
            xj[r][b]     = hi ? xv[8 + b]  : xv[b];
            xj[r][8 + b] = hi ? xv[24 + b] : xv[16 + b];
        }
        // packed bf16 full row (source of per-step scalar x_i)
        #pragma unroll
        for (int c = 0; c < 16; ++c)
            xpk[r][c] = pack2_bf16(xv[2 * c + 0], xv[2 * c + 1]);
    }

    f32x16 acc[2];
    #pragma unroll
    for (int r = 0; r < 2; ++r)
        #pragma unroll
        for (int e = 0; e < 16; ++e) acc[r][e] = 0.0f;

    __syncthreads();

    // ---- main K loop: 64 steps of K=16 (p = 16s .. 16s+15), fully unrolled ----
    #pragma unroll
    for (int s = 0; s < 64; ++s) {
        bf16x8 bfrag = *(const bf16x8*)(&btab[(s * 64 + lane) * 8]);
        const int ii   = s >> 1;         // i index (constant within step)
        const int hsel = (s & 1) * 8;    // which 8 of the lane's j-values
        #pragma unroll
        for (int r = 0; r < 2; ++r) {
            unsigned int w  = xpk[r][ii >> 1];
            unsigned int xb = (ii & 1) ? (w & 0xffff0000u) : (w << 16);
            float xi = __builtin_bit_cast(float, xb);   // x[n,i] (bf16 precision)
            bf16x8 a;
            #pragma unroll
            for (int b = 0; b < 8; ++b)
                a[b] = (__bf16)(xi * xj[r][hsel + b]);  // z[n,p] in bf16
            acc[r] = __builtin_amdgcn_mfma_f32_32x32x16_bf16(a, bfrag, acc[r], 0, 0, 0);
        }
    }

    // ---- store: col = lane&31 (k), row = (e&3) + 8*(e>>2) + 4*hi ----
    #pragma unroll
    for (int r = 0; r < 2; ++r) {
        long n0 = rowbase + r * 32;
        #pragma unroll
        for (int e = 0; e < 16; ++e) {
            int row = (e & 3) + 8 * (e >> 2) + 4 * hi;
            out[(n0 + row) * 32 + rl] = acc[r][e];
        }
    }
}

extern "C" void kernel_launch(void* const* d_in, const int* in_sizes, int n_in,
                              void* d_out, int out_size, void* d_ws, size_t ws_size,
                              hipStream_t stream) {
    const float* x = (const float*)d_in[0];
    const float* W = (const float*)d_in[1];
    float* out = (float*)d_out;
    int nrows = in_sizes[0] / 32;          // 262144
    int grid  = nrows / 512;               // 512 blocks (2 per CU)
    quadform_kernel<<<grid, 512, 0, stream>>>(x, W, out);
}

// Round 4
// 32.845 us; speedup vs baseline: 1.6442x; 1.5753x over previous
//
#include <hip/hip_runtime.h>

// out[n,k] = sum_{i,j} x[n,i] * W[k,i,j] * x[n,j]   (N=262144 rows, D=32)
// GEMM form: z[n, p=i*32+j] = x[n,i]*x[n,j];  out = z (N x 1024) @ Wf (1024 x 32),
// Wf[p][k] = W[k*1024 + p].  v_mfma_f32_32x32x16_f16, fp32 accumulate.
//
// R4 = R3 with the compile fix: __builtin_amdgcn_cvt_pkrtz returns
// __fp16 ext_vector(2); bit_cast it straight to unsigned int.
//
// R3 rationale (vs R2, which spilled ~29MB: WRITE 62MB vs 33 ideal, VGPR=88,
// MfmaUtil 11.6%):
//  - f16 datapath: A-fragments built with v_perm_b32 + v_pk_mul_f16 (products
//    come out packed; no per-element cvt). K-loop VALU ~12 ops/step vs ~28.
//  - register diet: packed-f16 row (16 regs/tile) + 8 hi-selected pair regs/tile
//    + acc 32 ~= 95 live -> fits 128-cap, launch_bounds(512,4).
//  - prologue never holds both tiles' fp32 rows concurrently.
// f16 also IMPROVES precision vs bf16 (2^-11 vs 2^-8 mantissa; |x|,|z|<30 ok).

typedef _Float16 f16x2 __attribute__((ext_vector_type(2)));
typedef _Float16 f16x8 __attribute__((ext_vector_type(8)));
typedef float    f32x16 __attribute__((ext_vector_type(16)));

static __device__ __forceinline__ unsigned int pk2_f16(float lo, float hi) {
    return __builtin_bit_cast(unsigned int, __builtin_amdgcn_cvt_pkrtz(lo, hi));
}

__global__ __launch_bounds__(512, 4)
void quadform_kernel(const float* __restrict__ x,
                     const float* __restrict__ W,
                     float* __restrict__ out) {
    // btab[(s*64 + lane)*8 + b] = f16 of Wf[16*s + (lane>>5)*8 + b][lane&31]
    __shared__ __align__(16) unsigned short btab[64 * 64 * 8];   // 64 KiB

    const int tid  = threadIdx.x;
    const int lane = tid & 63;
    const int wave = tid >> 6;
    const int hi   = lane >> 5;
    const int rl   = lane & 31;
    const long rowbase = (long)blockIdx.x * 512 + wave * 64;

    // ---- tile0 x loads issued first (latency hides under W-table build) ----
    float4 xv0[8];
    {
        const float4* xr = (const float4*)(x + (rowbase + rl) * 32);
        #pragma unroll
        for (int c = 0; c < 8; ++c) xv0[c] = xr[c];
    }

    // ---- build LDS B-table from global W (fp32 -> f16 fragments) ----
    #pragma unroll
    for (int f = 0; f < 8; ++f) {
        int idx = tid + f * 512;                 // 0..4095 fragments (s,l)
        int s = idx >> 6;
        int l = idx & 63;
        const float* src = W + (l & 31) * 1024 + s * 16 + ((l >> 5) << 3);
        float4 w0 = *(const float4*)(src);
        float4 w1 = *(const float4*)(src + 4);
        union { unsigned int ui[4]; uint4 u4; } pk;
        pk.ui[0] = pk2_f16(w0.x, w0.y);
        pk.ui[1] = pk2_f16(w0.z, w0.w);
        pk.ui[2] = pk2_f16(w1.x, w1.y);
        pk.ui[3] = pk2_f16(w1.z, w1.w);
        *(uint4*)(&btab[idx * 8]) = pk.u4;
    }

    // xpk[r][c]: packed f16 pair (x[2c], x[2c+1]) of this lane's row r.
    // xsel[r][q*4+t]: pair-reg feeding A-slots (b=2t,2t+1) for step parity q:
    //   j = q*16 + hi*8 + 2t  ->  pair index c = q*8 + hi*4 + t
    unsigned int xpk[2][16];
    unsigned int xsel[2][8];

    #pragma unroll
    for (int c = 0; c < 8; ++c) {
        xpk[0][2 * c + 0] = pk2_f16(xv0[c].x, xv0[c].y);
        xpk[0][2 * c + 1] = pk2_f16(xv0[c].z, xv0[c].w);
    }
    #pragma unroll
    for (int q = 0; q < 2; ++q)
        #pragma unroll
        for (int t = 0; t < 4; ++t)
            xsel[0][q * 4 + t] = hi ? xpk[0][q * 8 + 4 + t] : xpk[0][q * 8 + t];

    // ---- tile1 (fp32 regs of tile0 now dead) ----
    {
        float4 xv1[8];
        const float4* xr = (const float4*)(x + (rowbase + 32 + rl) * 32);
        #pragma unroll
        for (int c = 0; c < 8; ++c) xv1[c] = xr[c];
        #pragma unroll
        for (int c = 0; c < 8; ++c) {
            xpk[1][2 * c + 0] = pk2_f16(xv1[c].x, xv1[c].y);
            xpk[1][2 * c + 1] = pk2_f16(xv1[c].z, xv1[c].w);
        }
    }
    #pragma unroll
    for (int q = 0; q < 2; ++q)
        #pragma unroll
        for (int t = 0; t < 4; ++t)
            xsel[1][q * 4 + t] = hi ? xpk[1][q * 8 + 4 + t] : xpk[1][q * 8 + t];

    f32x16 acc[2];
    #pragma unroll
    for (int r = 0; r < 2; ++r)
        #pragma unroll
        for (int e = 0; e < 16; ++e) acc[r][e] = 0.0f;

    __syncthreads();

    // ---- main K loop: 64 steps of K=16 (p = 16s+k), fully unrolled ----
    #pragma unroll
    for (int s = 0; s < 64; ++s) {
        f16x8 bfrag = *(const f16x8*)(&btab[(s * 64 + lane) * 8]);
        const int ii = s >> 1;           // i (fixed within step)
        const int q  = s & 1;
        // duplicate x_i across an f16 pair: v_perm_b32 byte-select
        const unsigned int sel = (ii & 1) ? 0x03020302u : 0x01000100u;
        #pragma unroll
        for (int r = 0; r < 2; ++r) {
            unsigned int w = xpk[r][ii >> 1];
            f16x2 xi2 = __builtin_bit_cast(f16x2, __builtin_amdgcn_perm(w, w, sel));
            union { f16x8 v; unsigned int u[4]; } a;
            #pragma unroll
            for (int t = 0; t < 4; ++t) {
                f16x2 p = xi2 * __builtin_bit_cast(f16x2, xsel[r][q * 4 + t]); // v_pk_mul_f16
                a.u[t] = __builtin_bit_cast(unsigned int, p);
            }
            acc[r] = __builtin_amdgcn_mfma_f32_32x32x16_f16(a.v, bfrag, acc[r], 0, 0, 0);
        }
    }

    // ---- store: col = lane&31 (k), row = (e&3) + 8*(e>>2) + 4*hi ----
    #pragma unroll
    for (int r = 0; r < 2; ++r) {
        long n0 = rowbase + r * 32;
        #pragma unroll
        for (int e = 0; e < 16; ++e) {
            int row = (e & 3) + 8 * (e >> 2) + 4 * hi;
            out[(n0 + row) * 32 + rl] = acc[r][e];
        }
    }
}

extern "C" void kernel_launch(void* const* d_in, const int* in_sizes, int n_in,
                              void* d_out, int out_size, void* d_ws, size_t ws_size,
                              hipStream_t stream) {
    const float* x = (const float*)d_in[0];
    const float* W = (const float*)d_in[1];
    float* out = (float*)d_out;
    int nrows = in_sizes[0] / 32;          // 262144
    int grid  = nrows / 512;               // 512 blocks (2 per CU)
    quadform_kernel<<<grid, 512, 0, stream>>>(x, W, out);
}

// Round 5
// 31.510 us; speedup vs baseline: 1.7139x; 1.0424x over previous
//
#include <hip/hip_runtime.h>

// out[n,k] = sum_{i,j} x[n,i] * W[k,i,j] * x[n,j]   (N=262144 rows, D=32)
// GEMM form: z[n, p=i*32+j] = x[n,i]*x[n,j];  out = z (N x 1024) @ Wf (1024 x 32),
// Wf[p][k] = W[k*1024 + p].  v_mfma_f32_32x32x16_f16, fp32 accumulate.
//
// R5 change vs R4 (32.8us): x loads were 128B-strided per-lane scatters
// (64 cache lines per instruction, ~4.2M line-requests device-wide). Now:
// fully-coalesced float4 loads (lane i reads consecutive 16B), pack f16 in
// register, stage 40KB/block in LDS (inside the btab region, before btab is
// built; 80B row stride -> readback conflicts <=8-way, once per kernel),
// read back per-lane rows. K-loop / btab / W path / stores identical to R4.

typedef _Float16 f16x2 __attribute__((ext_vector_type(2)));
typedef _Float16 f16x8 __attribute__((ext_vector_type(8)));
typedef float    f32x16 __attribute__((ext_vector_type(16)));

static __device__ __forceinline__ unsigned int pk2_f16(float lo, float hi) {
    return __builtin_bit_cast(unsigned int, __builtin_amdgcn_cvt_pkrtz(lo, hi));
}

__global__ __launch_bounds__(512, 4)
void quadform_kernel(const float* __restrict__ x,
                     const float* __restrict__ W,
                     float* __restrict__ out) {
    // 64 KiB shared: first used as x-staging (40 KiB, wave-local), then as btab.
    // btab[(s*64 + lane)*8 + b] = f16 of Wf[16*s + (lane>>5)*8 + b][lane&31]
    __shared__ __align__(16) unsigned int smem[16384];

    const int tid  = threadIdx.x;
    const int lane = tid & 63;
    const int wave = tid >> 6;
    const int hi   = lane >> 5;
    const int rl   = lane & 31;
    const long rowbase = (long)blockIdx.x * 512 + wave * 64;

    // ---- coalesced x load: lane reads 16B at byte it*1024 + lane*16 ----
    float4 xg[8];
    {
        const float4* xsrc = (const float4*)(x + rowbase * 32);
        #pragma unroll
        for (int it = 0; it < 8; ++it) xg[it] = xsrc[it * 64 + lane];
    }

    // ---- pack to f16 pairs, stage wave-locally (row stride 80B = 20 u32) ----
    unsigned int* stage = smem + wave * 1280;     // 5120 B per wave
    #pragma unroll
    for (int it = 0; it < 8; ++it) {
        // flat f32 idx F = it*256 + lane*4 -> row R = F>>5, pair col cp = (F&31)/2
        int R  = it * 8 + (lane >> 3);
        int cp = (lane & 7) * 2;
        uint2 w2;
        w2.x = pk2_f16(xg[it].x, xg[it].y);
        w2.y = pk2_f16(xg[it].z, xg[it].w);
        *(uint2*)(stage + R * 20 + cp) = w2;      // 8B-aligned
    }

    // ---- read back this lane's 2 rows (wave-local; lgkmcnt auto) ----
    unsigned int xpk[2][16];   // packed f16 pair (x[2c], x[2c+1]) per row
    #pragma unroll
    for (int r = 0; r < 2; ++r) {
        int rlocal = r * 32 + rl;
        #pragma unroll
        for (int c = 0; c < 4; ++c) {
            uint4 v = *(const uint4*)(stage + rlocal * 20 + c * 4);
            xpk[r][c * 4 + 0] = v.x;
            xpk[r][c * 4 + 1] = v.y;
            xpk[r][c * 4 + 2] = v.z;
            xpk[r][c * 4 + 3] = v.w;
        }
    }
    __syncthreads();   // all waves done with staging before btab overwrites it

    // ---- build LDS B-table from global W (fp32 -> f16 fragments), as R4 ----
    unsigned short* btab = (unsigned short*)smem;
    #pragma unroll
    for (int f = 0; f < 8; ++f) {
        int idx = tid + f * 512;                 // 0..4095 fragments (s,l)
        int s = idx >> 6;
        int l = idx & 63;
        const float* src = W + (l & 31) * 1024 + s * 16 + ((l >> 5) << 3);
        float4 w0 = *(const float4*)(src);
        float4 w1 = *(const float4*)(src + 4);
        union { unsigned int ui[4]; uint4 u4; } pk;
        pk.ui[0] = pk2_f16(w0.x, w0.y);
        pk.ui[1] = pk2_f16(w0.z, w0.w);
        pk.ui[2] = pk2_f16(w1.x, w1.y);
        pk.ui[3] = pk2_f16(w1.z, w1.w);
        *(uint4*)(&btab[idx * 8]) = pk.u4;
    }

    // xsel[r][q*4+t]: pair-reg feeding A-slots (b=2t,2t+1) for step parity q:
    //   j = q*16 + hi*8 + 2t  ->  pair index c = q*8 + hi*4 + t
    unsigned int xsel[2][8];
    #pragma unroll
    for (int r = 0; r < 2; ++r)
        #pragma unroll
        for (int q = 0; q < 2; ++q)
            #pragma unroll
            for (int t = 0; t < 4; ++t)
                xsel[r][q * 4 + t] = hi ? xpk[r][q * 8 + 4 + t] : xpk[r][q * 8 + t];

    f32x16 acc[2];
    #pragma unroll
    for (int r = 0; r < 2; ++r)
        #pragma unroll
        for (int e = 0; e < 16; ++e) acc[r][e] = 0.0f;

    __syncthreads();

    // ---- main K loop: 64 steps of K=16 (p = 16s+k), fully unrolled ----
    #pragma unroll
    for (int s = 0; s < 64; ++s) {
        f16x8 bfrag = *(const f16x8*)(&btab[(s * 64 + lane) * 8]);
        const int ii = s >> 1;           // i (fixed within step)
        const int q  = s & 1;
        // duplicate x_i across an f16 pair: v_perm_b32 byte-select
        const unsigned int sel = (ii & 1) ? 0x03020302u : 0x01000100u;
        #pragma unroll
        for (int r = 0; r < 2; ++r) {
            unsigned int w = xpk[r][ii >> 1];
            f16x2 xi2 = __builtin_bit_cast(f16x2, __builtin_amdgcn_perm(w, w, sel));
            union { f16x8 v; unsigned int u[4]; } a;
            #pragma unroll
            for (int t = 0; t < 4; ++t) {
                f16x2 p = xi2 * __builtin_bit_cast(f16x2, xsel[r][q * 4 + t]); // v_pk_mul_f16
                a.u[t] = __builtin_bit_cast(unsigned int, p);
            }
            acc[r] = __builtin_amdgcn_mfma_f32_32x32x16_f16(a.v, bfrag, acc[r], 0, 0, 0);
        }
    }

    // ---- store: col = lane&31 (k), row = (e&3) + 8*(e>>2) + 4*hi ----
    #pragma unroll
    for (int r = 0; r < 2; ++r) {
        long n0 = rowbase + r * 32;
        #pragma unroll
        for (int e = 0; e < 16; ++e) {
            int row = (e & 3) + 8 * (e >> 2) + 4 * hi;
            out[(n0 + row) * 32 + rl] = acc[r][e];
        }
    }
}

extern "C" void kernel_launch(void* const* d_in, const int* in_sizes, int n_in,
                              void* d_out, int out_size, void* d_ws, size_t ws_size,
                              hipStream_t stream) {
    const float* x = (const float*)d_in[0];
    const float* W = (const float*)d_in[1];
    float* out = (float*)d_out;
    int nrows = in_sizes[0] / 32;          // 262144
    int grid  = nrows / 512;               // 512 blocks (2 per CU)
    quadform_kernel<<<grid, 512, 0, stream>>>(x, W, out);
}